// Round 2
// baseline (1926.267 us; speedup 1.0000x reference)
//
#include <hip/hip_runtime.h>
#include <math.h>

#define Bsz   2
#define Tlen  2048
#define Cdim  2048
#define NH    16
#define NKV   4
#define HD    128
#define KVW   (2*NKV*HD)      // 1024

typedef short  s16x8 __attribute__((ext_vector_type(8)));
typedef float  f32x4 __attribute__((ext_vector_type(4)));

// bf16 helpers (RNE), dependency-free
static __device__ __forceinline__ unsigned short f2bf(float f) {
    unsigned int u = __float_as_uint(f);
    u = u + 0x7FFFu + ((u >> 16) & 1u);
    return (unsigned short)(u >> 16);
}
static __device__ __forceinline__ float bf2f(unsigned short h) {
    return __uint_as_float(((unsigned int)h) << 16);
}

// ---------------------------------------------------------------------------
// split fp32 -> bf16 hi/lo (linear), 4 elems/thread
// ---------------------------------------------------------------------------
__global__ __launch_bounds__(256)
void split_bf(const float* __restrict__ in, unsigned short* __restrict__ hi,
              unsigned short* __restrict__ lo, int n4)
{
    int i = blockIdx.x * 256 + threadIdx.x;
    if (i >= n4) return;
    float4 v = reinterpret_cast<const float4*>(in)[i];
    ushort4 h, l;
    h.x = f2bf(v.x); l.x = f2bf(v.x - bf2f(h.x));
    h.y = f2bf(v.y); l.y = f2bf(v.y - bf2f(h.y));
    h.z = f2bf(v.z); l.z = f2bf(v.z - bf2f(h.z));
    h.w = f2bf(v.w); l.w = f2bf(v.w - bf2f(h.w));
    reinterpret_cast<ushort4*>(hi)[i] = h;
    reinterpret_cast<ushort4*>(lo)[i] = l;
}

// ---------------------------------------------------------------------------
// W[K][N] fp32 -> WT_hi/lo [N][K] bf16 (32x32 LDS tile transpose)
// grid (N/32, K/32), block (32,8)
// ---------------------------------------------------------------------------
__global__ __launch_bounds__(256)
void conv_T(const float* __restrict__ W, unsigned short* __restrict__ Thi,
            unsigned short* __restrict__ Tlo, int K, int N)
{
    __shared__ float t[32][33];
    const int tx = threadIdx.x;          // 0..31
    const int ty = threadIdx.y;          // 0..7
    const int n0 = blockIdx.x * 32, k0 = blockIdx.y * 32;
#pragma unroll
    for (int j = 0; j < 4; ++j)
        t[ty + j * 8][tx] = W[(size_t)(k0 + ty + j * 8) * N + n0 + tx];
    __syncthreads();
#pragma unroll
    for (int j = 0; j < 4; ++j) {
        float v = t[tx][ty + j * 8];                 // = W[k0+tx][n0+ty+j*8]
        unsigned short h = f2bf(v);
        unsigned short l = f2bf(v - bf2f(h));
        size_t o = (size_t)(n0 + ty + j * 8) * K + k0 + tx;
        Thi[o] = h; Tlo[o] = l;
    }
}

// ---------------------------------------------------------------------------
// Split-bf16 3-pass MFMA GEMM:  Out[M][N] fp32 = (Ah+Al)[M][K] x (Bh+Bl)^T
// A: [M][K] bf16 hi/lo.  B given TRANSPOSED: BT [N][K] bf16 hi/lo.
// BM=BN=128, BK=32, 256 thr = 4 waves (2x2), 64x64 out/wave, 4x4 16x16 frags.
// LDS row stride 40 halfwords (80 B): frag reads & stage writes 8-phase
// conflict-free (verified lane map: bank-group = (5*row + kg) % 8, uniform).
// ---------------------------------------------------------------------------
__global__ __launch_bounds__(256)
void gemm_bf3(const unsigned short* __restrict__ Ah, const unsigned short* __restrict__ Al,
              const unsigned short* __restrict__ Bh, const unsigned short* __restrict__ Bl,
              float* __restrict__ Out, int M, int N, int K)
{
    __shared__ unsigned short Ahs[128][40], Als[128][40], Bhs[128][40], Bls[128][40];

    const int tid  = threadIdx.x;
    const int lane = tid & 63;
    const int w    = tid >> 6;
    const int wm   = w >> 1, wn = w & 1;
    const int m0   = blockIdx.y * 128, n0 = blockIdx.x * 128;
    const int lr   = lane & 15;          // frag row/col
    const int kg   = lane >> 4;          // k-group (and C/D row-group)

    const int srow = tid >> 2;           // staging: 0..63
    const int skg  = tid & 3;

    f32x4 acc[4][4];
#pragma unroll
    for (int i = 0; i < 4; ++i)
#pragma unroll
        for (int j = 0; j < 4; ++j) acc[i][j] = (f32x4){0.f, 0.f, 0.f, 0.f};

    for (int kt = 0; kt < K; kt += 32) {
#pragma unroll
        for (int t = 0; t < 2; ++t) {
            const int row = srow + t * 64;
            const size_t ga = (size_t)(m0 + row) * K + kt + skg * 8;
            const size_t gb = (size_t)(n0 + row) * K + kt + skg * 8;
            *reinterpret_cast<s16x8*>(&Ahs[row][skg * 8]) =
                *reinterpret_cast<const s16x8*>(&Ah[ga]);
            *reinterpret_cast<s16x8*>(&Als[row][skg * 8]) =
                *reinterpret_cast<const s16x8*>(&Al[ga]);
            *reinterpret_cast<s16x8*>(&Bhs[row][skg * 8]) =
                *reinterpret_cast<const s16x8*>(&Bh[gb]);
            *reinterpret_cast<s16x8*>(&Bls[row][skg * 8]) =
                *reinterpret_cast<const s16x8*>(&Bl[gb]);
        }
        __syncthreads();

        s16x8 ah[4], al[4], bh[4], bl[4];
#pragma unroll
        for (int f = 0; f < 4; ++f) {
            ah[f] = *reinterpret_cast<const s16x8*>(&Ahs[wm * 64 + f * 16 + lr][kg * 8]);
            al[f] = *reinterpret_cast<const s16x8*>(&Als[wm * 64 + f * 16 + lr][kg * 8]);
            bh[f] = *reinterpret_cast<const s16x8*>(&Bhs[wn * 64 + f * 16 + lr][kg * 8]);
            bl[f] = *reinterpret_cast<const s16x8*>(&Bls[wn * 64 + f * 16 + lr][kg * 8]);
        }
#pragma unroll
        for (int mf = 0; mf < 4; ++mf)
#pragma unroll
            for (int nf = 0; nf < 4; ++nf)
                acc[mf][nf] = __builtin_amdgcn_mfma_f32_16x16x32_bf16(
                    ah[mf], bh[nf], acc[mf][nf], 0, 0, 0);
#pragma unroll
        for (int mf = 0; mf < 4; ++mf)
#pragma unroll
            for (int nf = 0; nf < 4; ++nf)
                acc[mf][nf] = __builtin_amdgcn_mfma_f32_16x16x32_bf16(
                    ah[mf], bl[nf], acc[mf][nf], 0, 0, 0);
#pragma unroll
        for (int mf = 0; mf < 4; ++mf)
#pragma unroll
            for (int nf = 0; nf < 4; ++nf)
                acc[mf][nf] = __builtin_amdgcn_mfma_f32_16x16x32_bf16(
                    al[mf], bh[nf], acc[mf][nf], 0, 0, 0);
        __syncthreads();
    }

    // C/D layout (m89/m91 verified): col = lane&15, row = (lane>>4)*4 + j
#pragma unroll
    for (int mf = 0; mf < 4; ++mf)
#pragma unroll
        for (int nf = 0; nf < 4; ++nf)
#pragma unroll
            for (int j = 0; j < 4; ++j)
                Out[(size_t)(m0 + wm * 64 + mf * 16 + kg * 4 + j) * N
                    + (n0 + wn * 64 + nf * 16 + lr)] = acc[mf][nf][j];
}

// ---------------------------------------------------------------------------
// RoPE in-place: buf[rows][stride] fp32, heads of 128, pairs (d, d+64)
// ---------------------------------------------------------------------------
__global__ void rope_f32(float* __restrict__ buf, int rows, int heads, int stride)
{
    int idx = blockIdx.x * blockDim.x + threadIdx.x;
    int total = rows * heads * 64;
    if (idx >= total) return;
    int d = idx & 63;
    int h = (idx >> 6) % heads;
    int r = idx / (64 * heads);
    int t = r % Tlen;

    float e     = (float)(2 * d) * (1.0f / 128.0f);
    float theta = powf(10000.0f, -e);
    float f     = (float)t * theta;
    float s, c;
    sincosf(f, &s, &c);

    float* p = buf + (size_t)r * stride + h * HD;
    float x1 = p[d];
    float x2 = p[d + 64];
    p[d]      = x1 * c - x2 * s;
    p[d + 64] = x2 * c + x1 * s;
}

// ---------------------------------------------------------------------------
// Flash-style causal attention, fp32; writes bf16 hi/lo output directly.
// Q: [B*T][2048] fp32. KV: [B*T][1024] fp32. Yhi/Ylo: [B*T][2048] bf16.
// ---------------------------------------------------------------------------
__global__ __launch_bounds__(256)
void attn_f32(const float* __restrict__ Q, const float* __restrict__ KV,
              unsigned short* __restrict__ Yhi, unsigned short* __restrict__ Ylo)
{
    __shared__ float Ks[32][128];
    __shared__ float Vs[32][128];

    const int tid  = threadIdx.x;
    const int lane = tid & 63;
    const int w    = tid >> 6;        // wave 0..3
    const int r5   = lane & 15;
    const int dg   = lane >> 4;       // 0..3
    const int d0   = dg * 32;

    const int qt = blockIdx.x & 15;   // T/128 = 16
    const int bh = blockIdx.x >> 4;
    const int b  = bh >> 4;           // NH = 16
    const int h  = bh & 15;
    const int kh = h >> 2;            // NREP = 4

    const int   row0 = qt * 128 + w * 32 + r5;
    const int   row1 = row0 + 16;
    const size_t qb0 = ((size_t)(b * Tlen + row0)) * Cdim + h * HD + d0;
    const size_t qb1 = ((size_t)(b * Tlen + row1)) * Cdim + h * HD + d0;

    const float scale = 0.08838834764831845f;   // 1/sqrt(128)

    float q0[32], q1[32], o0[32], o1[32];
#pragma unroll
    for (int j = 0; j < 8; ++j) {
        float4 v = *reinterpret_cast<const float4*>(&Q[qb0 + 4 * j]);
        q0[4*j+0] = v.x * scale; q0[4*j+1] = v.y * scale;
        q0[4*j+2] = v.z * scale; q0[4*j+3] = v.w * scale;
        float4 u = *reinterpret_cast<const float4*>(&Q[qb1 + 4 * j]);
        q1[4*j+0] = u.x * scale; q1[4*j+1] = u.y * scale;
        q1[4*j+2] = u.z * scale; q1[4*j+3] = u.w * scale;
    }
#pragma unroll
    for (int j = 0; j < 32; ++j) { o0[j] = 0.f; o1[j] = 0.f; }
    float m0 = -INFINITY, m1 = -INFINITY, l0 = 0.f, l1 = 0.f;

    const int ntiles = (qt + 1) * 4;

    for (int kt = 0; kt < ntiles; ++kt) {
        const int ks = kt * 32;
#pragma unroll
        for (int i = 0; i < 4; ++i) {
            int idx = tid + i * 256;
            int key = idx >> 5;
            int c4  = (idx & 31) << 2;
            size_t gbase = ((size_t)(b * Tlen + ks + key)) * KVW + kh * 128 + c4;
            *reinterpret_cast<float4*>(&Ks[key][c4]) =
                *reinterpret_cast<const float4*>(&KV[gbase]);
            *reinterpret_cast<float4*>(&Vs[key][c4]) =
                *reinterpret_cast<const float4*>(&KV[gbase + 512]);
        }
        __syncthreads();

        float p0[32], p1[32];
        float tm0 = -INFINITY, tm1 = -INFINITY;
#pragma unroll
        for (int kk = 0; kk < 32; ++kk) {
            float s0 = 0.f, s1 = 0.f;
#pragma unroll
            for (int j = 0; j < 8; ++j) {
                float4 k4 = *reinterpret_cast<const float4*>(&Ks[kk][d0 + 4 * j]);
                s0 = fmaf(q0[4*j+0], k4.x, s0); s0 = fmaf(q0[4*j+1], k4.y, s0);
                s0 = fmaf(q0[4*j+2], k4.z, s0); s0 = fmaf(q0[4*j+3], k4.w, s0);
                s1 = fmaf(q1[4*j+0], k4.x, s1); s1 = fmaf(q1[4*j+1], k4.y, s1);
                s1 = fmaf(q1[4*j+2], k4.z, s1); s1 = fmaf(q1[4*j+3], k4.w, s1);
            }
            s0 += __shfl_xor(s0, 16); s0 += __shfl_xor(s0, 32);
            s1 += __shfl_xor(s1, 16); s1 += __shfl_xor(s1, 32);
            int kg = ks + kk;
            s0 = (kg <= row0) ? s0 : -3.402823466e38f;
            s1 = (kg <= row1) ? s1 : -3.402823466e38f;
            p0[kk] = s0; p1[kk] = s1;
            tm0 = fmaxf(tm0, s0); tm1 = fmaxf(tm1, s1);
        }

        float nm0 = fmaxf(m0, tm0), nm1 = fmaxf(m1, tm1);
        float c0 = __expf(m0 - nm0), c1 = __expf(m1 - nm1);
        float sum0 = 0.f, sum1 = 0.f;
#pragma unroll
        for (int kk = 0; kk < 32; ++kk) {
            p0[kk] = __expf(p0[kk] - nm0); sum0 += p0[kk];
            p1[kk] = __expf(p1[kk] - nm1); sum1 += p1[kk];
        }
        l0 = l0 * c0 + sum0; l1 = l1 * c1 + sum1;
        m0 = nm0; m1 = nm1;
#pragma unroll
        for (int j = 0; j < 32; ++j) { o0[j] *= c0; o1[j] *= c1; }

#pragma unroll
        for (int kk = 0; kk < 32; ++kk) {
            float pa = p0[kk], pb = p1[kk];
#pragma unroll
            for (int j = 0; j < 8; ++j) {
                float4 v4 = *reinterpret_cast<const float4*>(&Vs[kk][d0 + 4 * j]);
                o0[4*j+0] = fmaf(pa, v4.x, o0[4*j+0]);
                o0[4*j+1] = fmaf(pa, v4.y, o0[4*j+1]);
                o0[4*j+2] = fmaf(pa, v4.z, o0[4*j+2]);
                o0[4*j+3] = fmaf(pa, v4.w, o0[4*j+3]);
                o1[4*j+0] = fmaf(pb, v4.x, o1[4*j+0]);
                o1[4*j+1] = fmaf(pb, v4.y, o1[4*j+1]);
                o1[4*j+2] = fmaf(pb, v4.z, o1[4*j+2]);
                o1[4*j+3] = fmaf(pb, v4.w, o1[4*j+3]);
            }
        }
        __syncthreads();
    }

    const float r0 = 1.0f / l0, r1 = 1.0f / l1;
#pragma unroll
    for (int j = 0; j < 8; ++j) {
        float a0 = o0[4*j+0]*r0, a1 = o0[4*j+1]*r0, a2 = o0[4*j+2]*r0, a3 = o0[4*j+3]*r0;
        ushort4 h, l;
        h.x = f2bf(a0); l.x = f2bf(a0 - bf2f(h.x));
        h.y = f2bf(a1); l.y = f2bf(a1 - bf2f(h.y));
        h.z = f2bf(a2); l.z = f2bf(a2 - bf2f(h.z));
        h.w = f2bf(a3); l.w = f2bf(a3 - bf2f(h.w));
        *reinterpret_cast<ushort4*>(&Yhi[qb0 + 4 * j]) = h;
        *reinterpret_cast<ushort4*>(&Ylo[qb0 + 4 * j]) = l;
        float b0 = o1[4*j+0]*r1, b1 = o1[4*j+1]*r1, b2 = o1[4*j+2]*r1, b3 = o1[4*j+3]*r1;
        h.x = f2bf(b0); l.x = f2bf(b0 - bf2f(h.x));
        h.y = f2bf(b1); l.y = f2bf(b1 - bf2f(h.y));
        h.z = f2bf(b2); l.z = f2bf(b2 - bf2f(h.z));
        h.w = f2bf(b3); l.w = f2bf(b3 - bf2f(h.w));
        *reinterpret_cast<ushort4*>(&Yhi[qb1 + 4 * j]) = h;
        *reinterpret_cast<ushort4*>(&Ylo[qb1 + 4 * j]) = l;
    }
}

// ---------------------------------------------------------------------------
extern "C" void kernel_launch(void* const* d_in, const int* in_sizes, int n_in,
                              void* d_out, int out_size, void* d_ws, size_t ws_size,
                              hipStream_t stream)
{
    const float* x     = (const float*)d_in[0];
    const float* Wq    = (const float*)d_in[1];
    const float* Wkv   = (const float*)d_in[2];
    const float* Wproj = (const float*)d_in[3];
    float* out = (float*)d_out;

    const int M = Bsz * Tlen;                         // 4096

    // workspace layout (bytes):
    char* p = (char*)d_ws;
    float* q_ws  = (float*)p;            p += (size_t)M * Cdim * 4;      // 33.55 MB
    float* kv_ws = (float*)p;            p += (size_t)M * KVW  * 4;      // 16.78 MB
    unsigned short* xhi = (unsigned short*)p; p += (size_t)M * Cdim * 2; // 16.78 MB (reused as yhi)
    unsigned short* xlo = (unsigned short*)p; p += (size_t)M * Cdim * 2; // 16.78 MB (reused as ylo)
    unsigned short* wqh = (unsigned short*)p; p += (size_t)Cdim * Cdim * 2;
    unsigned short* wql = (unsigned short*)p; p += (size_t)Cdim * Cdim * 2;
    unsigned short* wkh = (unsigned short*)p; p += (size_t)KVW  * Cdim * 2;
    unsigned short* wkl = (unsigned short*)p; p += (size_t)KVW  * Cdim * 2;
    unsigned short* wph = (unsigned short*)p; p += (size_t)Cdim * Cdim * 2;
    unsigned short* wpl = (unsigned short*)p; p += (size_t)Cdim * Cdim * 2;

    dim3 blk(256);
    dim3 tblk(32, 8);

    // 1. convert inputs
    split_bf<<<dim3((M * Cdim / 4 + 255) / 256), blk, 0, stream>>>(x, xhi, xlo, M * Cdim / 4);
    conv_T<<<dim3(Cdim / 32, Cdim / 32), tblk, 0, stream>>>(Wq,    wqh, wql, Cdim, Cdim);
    conv_T<<<dim3(KVW  / 32, Cdim / 32), tblk, 0, stream>>>(Wkv,   wkh, wkl, Cdim, KVW);
    conv_T<<<dim3(Cdim / 32, Cdim / 32), tblk, 0, stream>>>(Wproj, wph, wpl, Cdim, Cdim);

    // 2. Q and KV projections (split-bf16 MFMA)
    gemm_bf3<<<dim3(Cdim / 128, M / 128), blk, 0, stream>>>(xhi, xlo, wqh, wql, q_ws,  M, Cdim, Cdim);
    gemm_bf3<<<dim3(KVW  / 128, M / 128), blk, 0, stream>>>(xhi, xlo, wkh, wkl, kv_ws, M, KVW,  Cdim);

    // 3. RoPE
    rope_f32<<<dim3((M * NH  * 64) / 256), blk, 0, stream>>>(q_ws,  M, NH,  Cdim);
    rope_f32<<<dim3((M * NKV * 64) / 256), blk, 0, stream>>>(kv_ws, M, NKV, KVW);

    // 4. attention (fp32), writes bf16 hi/lo into xhi/xlo (x no longer needed)
    attn_f32<<<dim3(Bsz * NH * (Tlen / 128)), blk, 0, stream>>>(q_ws, kv_ws, xhi, xlo);

    // 5. output projection
    gemm_bf3<<<dim3(Cdim / 128, M / 128), blk, 0, stream>>>(xhi, xlo, wph, wpl, out, M, Cdim, Cdim);
}

// Round 4
// 779.679 us; speedup vs baseline: 2.4706x; 2.4706x over previous
//
#include <hip/hip_runtime.h>
#include <math.h>

#define Bsz   2
#define Tlen  2048
#define Cdim  2048
#define NH    16
#define NKV   4
#define HD    128
#define KVW   1024

typedef short    s16x8 __attribute__((ext_vector_type(8)));
typedef _Float16 f16x8 __attribute__((ext_vector_type(8)));
typedef float    f32x4 __attribute__((ext_vector_type(4)));

static __device__ __forceinline__ unsigned short f2bf(float f) {
    unsigned int u = __float_as_uint(f);
    u = u + 0x7FFFu + ((u >> 16) & 1u);
    return (unsigned short)(u >> 16);
}
static __device__ __forceinline__ float bf2f(unsigned short h) {
    return __uint_as_float(((unsigned int)h) << 16);
}

#define GLL16(g, l) __builtin_amdgcn_global_load_lds( \
    (const __attribute__((address_space(1))) unsigned int*)(const void*)(g), \
    (__attribute__((address_space(3))) unsigned int*)(void*)(l), 16, 0, 0)

// ---------------------------------------------------------------------------
// split fp32 -> bf16 hi/lo (linear), 4 elems/thread
// ---------------------------------------------------------------------------
__global__ __launch_bounds__(256)
void split_bf(const float* __restrict__ in, unsigned short* __restrict__ hi,
              unsigned short* __restrict__ lo, int n4)
{
    int i = blockIdx.x * 256 + threadIdx.x;
    if (i >= n4) return;
    float4 v = reinterpret_cast<const float4*>(in)[i];
    ushort4 h, l;
    h.x = f2bf(v.x); l.x = f2bf(v.x - bf2f(h.x));
    h.y = f2bf(v.y); l.y = f2bf(v.y - bf2f(h.y));
    h.z = f2bf(v.z); l.z = f2bf(v.z - bf2f(h.z));
    h.w = f2bf(v.w); l.w = f2bf(v.w - bf2f(h.w));
    reinterpret_cast<ushort4*>(hi)[i] = h;
    reinterpret_cast<ushort4*>(lo)[i] = l;
}

// ---------------------------------------------------------------------------
// W[K][N] fp32 -> WT_hi/lo [N][K] bf16 (32x32 LDS tile transpose)
// ---------------------------------------------------------------------------
__global__ __launch_bounds__(256)
void conv_T(const float* __restrict__ W, unsigned short* __restrict__ Thi,
            unsigned short* __restrict__ Tlo, int K, int N)
{
    __shared__ float t[32][33];
    const int tx = threadIdx.x;
    const int ty = threadIdx.y;
    const int n0 = blockIdx.x * 32, k0 = blockIdx.y * 32;
#pragma unroll
    for (int j = 0; j < 4; ++j)
        t[ty + j * 8][tx] = W[(size_t)(k0 + ty + j * 8) * N + n0 + tx];
    __syncthreads();
#pragma unroll
    for (int j = 0; j < 4; ++j) {
        float v = t[tx][ty + j * 8];
        unsigned short h = f2bf(v);
        unsigned short l = f2bf(v - bf2f(h));
        size_t o = (size_t)(n0 + ty + j * 8) * K + k0 + tx;
        Thi[o] = h; Tlo[o] = l;
    }
}

// ---------------------------------------------------------------------------
// Split-bf16 3-pass MFMA GEMM (unchanged, proven)
// ---------------------------------------------------------------------------
__global__ __launch_bounds__(256)
void gemm_bf3(const unsigned short* __restrict__ Ah, const unsigned short* __restrict__ Al,
              const unsigned short* __restrict__ Bh, const unsigned short* __restrict__ Bl,
              float* __restrict__ Out, int M, int N, int K)
{
    __shared__ unsigned short Ahs[128][40], Als[128][40], Bhs[128][40], Bls[128][40];

    const int tid  = threadIdx.x;
    const int lane = tid & 63;
    const int w    = tid >> 6;
    const int wm   = w >> 1, wn = w & 1;
    const int m0   = blockIdx.y * 128, n0 = blockIdx.x * 128;
    const int lr   = lane & 15;
    const int kg   = lane >> 4;

    const int srow = tid >> 2;
    const int skg  = tid & 3;

    f32x4 acc[4][4];
#pragma unroll
    for (int i = 0; i < 4; ++i)
#pragma unroll
        for (int j = 0; j < 4; ++j) acc[i][j] = (f32x4){0.f, 0.f, 0.f, 0.f};

    for (int kt = 0; kt < K; kt += 32) {
#pragma unroll
        for (int t = 0; t < 2; ++t) {
            const int row = srow + t * 64;
            const size_t ga = (size_t)(m0 + row) * K + kt + skg * 8;
            const size_t gb = (size_t)(n0 + row) * K + kt + skg * 8;
            *reinterpret_cast<s16x8*>(&Ahs[row][skg * 8]) =
                *reinterpret_cast<const s16x8*>(&Ah[ga]);
            *reinterpret_cast<s16x8*>(&Als[row][skg * 8]) =
                *reinterpret_cast<const s16x8*>(&Al[ga]);
            *reinterpret_cast<s16x8*>(&Bhs[row][skg * 8]) =
                *reinterpret_cast<const s16x8*>(&Bh[gb]);
            *reinterpret_cast<s16x8*>(&Bls[row][skg * 8]) =
                *reinterpret_cast<const s16x8*>(&Bl[gb]);
        }
        __syncthreads();

        s16x8 ah[4], al[4], bh[4], bl[4];
#pragma unroll
        for (int f = 0; f < 4; ++f) {
            ah[f] = *reinterpret_cast<const s16x8*>(&Ahs[wm * 64 + f * 16 + lr][kg * 8]);
            al[f] = *reinterpret_cast<const s16x8*>(&Als[wm * 64 + f * 16 + lr][kg * 8]);
            bh[f] = *reinterpret_cast<const s16x8*>(&Bhs[wn * 64 + f * 16 + lr][kg * 8]);
            bl[f] = *reinterpret_cast<const s16x8*>(&Bls[wn * 64 + f * 16 + lr][kg * 8]);
        }
#pragma unroll
        for (int mf = 0; mf < 4; ++mf)
#pragma unroll
            for (int nf = 0; nf < 4; ++nf)
                acc[mf][nf] = __builtin_amdgcn_mfma_f32_16x16x32_bf16(
                    ah[mf], bh[nf], acc[mf][nf], 0, 0, 0);
#pragma unroll
        for (int mf = 0; mf < 4; ++mf)
#pragma unroll
            for (int nf = 0; nf < 4; ++nf)
                acc[mf][nf] = __builtin_amdgcn_mfma_f32_16x16x32_bf16(
                    ah[mf], bl[nf], acc[mf][nf], 0, 0, 0);
#pragma unroll
        for (int mf = 0; mf < 4; ++mf)
#pragma unroll
            for (int nf = 0; nf < 4; ++nf)
                acc[mf][nf] = __builtin_amdgcn_mfma_f32_16x16x32_bf16(
                    al[mf], bh[nf], acc[mf][nf], 0, 0, 0);
        __syncthreads();
    }

#pragma unroll
    for (int mf = 0; mf < 4; ++mf)
#pragma unroll
        for (int nf = 0; nf < 4; ++nf)
#pragma unroll
            for (int j = 0; j < 4; ++j)
                Out[(size_t)(m0 + wm * 64 + mf * 16 + kg * 4 + j) * N
                    + (n0 + wn * 64 + nf * 16 + lr)] = acc[mf][nf][j];
}

// ---------------------------------------------------------------------------
// q_prep: q_ws [B,T,2048] f32 -> RoPE -> *scale -> Qh/Ql [B,H,T,128] bf16
// ---------------------------------------------------------------------------
__global__ __launch_bounds__(256)
void q_prep(const float* __restrict__ q_ws, unsigned short* __restrict__ Qh,
            unsigned short* __restrict__ Ql)
{
    int i = blockIdx.x * 256 + threadIdx.x;       // (b,h,t,j)
    int j = i & 63;
    int t = (i >> 6) & 2047;
    int h = (i >> 17) & 15;
    int b = i >> 21;
    const float scale = 0.08838834764831845f;     // 1/sqrt(128)
    size_t src = ((size_t)(b * Tlen + t)) * Cdim + h * HD;
    float x1 = q_ws[src + j], x2 = q_ws[src + j + 64];
    float theta = powf(10000.0f, -(float)(2 * j) * (1.0f / 128.0f));
    float s, c; sincosf((float)t * theta, &s, &c);
    float o1 = (x1 * c - x2 * s) * scale;
    float o2 = (x2 * c + x1 * s) * scale;
    size_t dst = ((size_t)((b * NH + h) * Tlen + t)) * HD;
    unsigned short h1 = f2bf(o1), h2 = f2bf(o2);
    Qh[dst + j] = h1;       Ql[dst + j]      = f2bf(o1 - bf2f(h1));
    Qh[dst + j + 64] = h2;  Ql[dst + j + 64] = f2bf(o2 - bf2f(h2));
}

// ---------------------------------------------------------------------------
// k_prep: kv_ws K-part -> RoPE -> Kh/Kl [B,KV,T,128] bf16, 16B-chunk XOR swizzle
// elem(t,d) = row*128 + (((d>>3) ^ (t&7))<<3) + (d&7)
// ---------------------------------------------------------------------------
__global__ __launch_bounds__(256)
void k_prep(const float* __restrict__ kv_ws, unsigned short* __restrict__ Kh,
            unsigned short* __restrict__ Kl)
{
    int i = blockIdx.x * 256 + threadIdx.x;       // (b,kh,t,j)
    int j = i & 63;
    int t = (i >> 6) & 2047;
    int kh = (i >> 17) & 3;
    int b = i >> 19;
    size_t src = ((size_t)(b * Tlen + t)) * KVW + kh * HD;
    float x1 = kv_ws[src + j], x2 = kv_ws[src + j + 64];
    float theta = powf(10000.0f, -(float)(2 * j) * (1.0f / 128.0f));
    float s, c; sincosf((float)t * theta, &s, &c);
    float o1 = x1 * c - x2 * s;
    float o2 = x2 * c + x1 * s;
    size_t row = ((size_t)((b * NKV + kh) * Tlen + t)) * HD;
    int tw = t & 7;
    size_t e1 = row + ((((j >> 3) ^ tw) << 3) | (j & 7));
    size_t e2 = row + (((((j >> 3) + 8) ^ tw) << 3) | (j & 7));
    unsigned short h1 = f2bf(o1), h2 = f2bf(o2);
    Kh[e1] = h1; Kl[e1] = f2bf(o1 - bf2f(h1));
    Kh[e2] = h2; Kl[e2] = f2bf(o2 - bf2f(h2));
}

// ---------------------------------------------------------------------------
// v_prep: kv_ws V-part -> Vh/Vl [B,KV,128,T] fp16 transposed, swizzled:
// elem(d,t) = row(d)*2048 + (t&~63) + ((((t&63)>>3) ^ (d&7))<<3) + (t&7)
// ---------------------------------------------------------------------------
__global__ __launch_bounds__(256)
void v_prep(const float* __restrict__ kv_ws, unsigned short* __restrict__ Vh,
            unsigned short* __restrict__ Vl)
{
    __shared__ float tile[32][33];
    int tx = threadIdx.x, ty = threadIdx.y;
    int t0 = blockIdx.x * 32;
    int z  = blockIdx.y;                 // (b*NKV+kh)*4 + dblk
    int dblk = z & 3;
    int bk   = z >> 2;                   // b*NKV + kh
    int d0 = dblk * 32;
    int b = bk >> 2, kh = bk & 3;
#pragma unroll
    for (int jj = 0; jj < 4; ++jj) {
        int t = t0 + ty + jj * 8;
        tile[ty + jj * 8][tx] =
            kv_ws[((size_t)(b * Tlen + t)) * KVW + 512 + kh * HD + d0 + tx];
    }
    __syncthreads();
#pragma unroll
    for (int jj = 0; jj < 4; ++jj) {
        int d = d0 + ty + jj * 8;
        int t = t0 + tx;
        float v = tile[tx][ty + jj * 8];
        _Float16 vh = (_Float16)v;
        _Float16 vl = (_Float16)(v - (float)vh);
        size_t e = ((size_t)bk * HD + d) * Tlen + (t & ~63)
                 + ((((t & 63) >> 3) ^ (d & 7)) << 3) + (t & 7);
        Vh[e] = __builtin_bit_cast(unsigned short, vh);
        Vl[e] = __builtin_bit_cast(unsigned short, vl);
    }
}

// ---------------------------------------------------------------------------
// MFMA flash attention. Block = (b,h,128 q-rows), 4 waves x 32 q-rows.
// KBLK=64. QK: bf16 3-pass; PV: P fp16 x V fp16 hi/lo 2-pass.
// LDS 64KB: Abuf = Kh|Kl (P aliases Kh region between barriers); Bbuf = Vth|Vtl.
// Swizzle discipline (rule 21): layouts are swizzled ONCE in prep; staging
// copies LINEARLY (global_load_lds); reads apply the same involution.
// ---------------------------------------------------------------------------
__global__ __launch_bounds__(256, 2)
void attn_mfma(const unsigned short* __restrict__ Qh, const unsigned short* __restrict__ Ql,
               const unsigned short* __restrict__ Kh, const unsigned short* __restrict__ Kl,
               const unsigned short* __restrict__ Vh, const unsigned short* __restrict__ Vl,
               unsigned short* __restrict__ Yhi, unsigned short* __restrict__ Ylo)
{
    __shared__ __align__(16) unsigned short Abuf[16384];  // Kh[0:8192] Kl[8192:]; P=Abuf[0:8192]
    __shared__ __align__(16) unsigned short Bbuf[16384];  // Vth[0:8192] Vtl[8192:]

    const int tid  = threadIdx.x;
    const int lane = tid & 63;
    const int w    = tid >> 6;
    const int lr   = lane & 15;
    const int kg   = lane >> 4;

    const int bh  = blockIdx.x & 31;
    const int qb  = 15 - (blockIdx.x >> 5);    // heaviest first
    const int b   = bh >> 4, h = bh & 15;
    const int kh  = h >> 2;
    const int q0  = qb * 128;
    const int wq0 = q0 + w * 32;

    // ---- Q fragments (registers, once per block) ----
    const size_t qrowbase = (size_t)((b * NH + h) * Tlen);
    s16x8 qfh[2][4], qfl[2][4];
#pragma unroll
    for (int mf = 0; mf < 2; ++mf)
#pragma unroll
        for (int s = 0; s < 4; ++s) {
            size_t e = (qrowbase + wq0 + mf * 16 + lr) * HD + (4 * s + kg) * 8;
            qfh[mf][s] = *reinterpret_cast<const s16x8*>(&Qh[e]);
            qfl[mf][s] = *reinterpret_cast<const s16x8*>(&Ql[e]);
        }

    f32x4 O[2][8];
#pragma unroll
    for (int mf = 0; mf < 2; ++mf)
#pragma unroll
        for (int df = 0; df < 8; ++df) O[mf][df] = (f32x4){0.f, 0.f, 0.f, 0.f};
    float mrow[2][4], lrow[2][4];
#pragma unroll
    for (int mf = 0; mf < 2; ++mf)
#pragma unroll
        for (int jj = 0; jj < 4; ++jj) { mrow[mf][jj] = -3.0e38f; lrow[mf][jj] = 0.f; }

    const size_t kbase = (size_t)((b * NKV + kh) * Tlen) * HD;   // elem base
    const size_t vbase = (size_t)(b * NKV + kh) * HD * Tlen;     // elem base

    const int nt = 2 * (qb + 1);

    for (int kt = 0; kt < nt; ++kt) {
        const int ks = kt * 64;

        // ---- stage K (32KB) + V (32KB): global_load_lds 16B, LINEAR copy ----
#pragma unroll
        for (int i = 0; i < 4; ++i) {
            int c = w * 4 + i;                 // 1KB chunk id, 0..15
            int L = c * 64 + lane;             // 16B unit within tile
            GLL16(&Kh[kbase + (size_t)ks * HD + (size_t)L * 8], &Abuf[c * 512]);
            GLL16(&Kl[kbase + (size_t)ks * HD + (size_t)L * 8], &Abuf[8192 + c * 512]);
            int d = L >> 3, cc = L & 7;
            size_t vsrc = vbase + (size_t)d * Tlen + ks + cc * 8;   // LINEAR (fix)
            GLL16(&Vh[vsrc], &Bbuf[c * 512]);
            GLL16(&Vl[vsrc], &Bbuf[8192 + c * 512]);
        }
        asm volatile("s_waitcnt vmcnt(0)" ::: "memory");
        __syncthreads();

        // ---- QK^T (3-pass split bf16) ----
        f32x4 S[2][4];
#pragma unroll
        for (int mf = 0; mf < 2; ++mf)
#pragma unroll
            for (int f = 0; f < 4; ++f) S[mf][f] = (f32x4){0.f, 0.f, 0.f, 0.f};

#pragma unroll
        for (int s = 0; s < 4; ++s) {
            s16x8 khf[4], klf[4];
#pragma unroll
            for (int f = 0; f < 4; ++f) {
                int key = f * 16 + lr;
                int e = key * 128 + (((4 * s + kg) ^ (key & 7)) << 3);
                khf[f] = *reinterpret_cast<const s16x8*>(&Abuf[e]);
                klf[f] = *reinterpret_cast<const s16x8*>(&Abuf[8192 + e]);
            }
#pragma unroll
            for (int mf = 0; mf < 2; ++mf)
#pragma unroll
                for (int f = 0; f < 4; ++f) {
                    S[mf][f] = __builtin_amdgcn_mfma_f32_16x16x32_bf16(qfh[mf][s], khf[f], S[mf][f], 0, 0, 0);
                    S[mf][f] = __builtin_amdgcn_mfma_f32_16x16x32_bf16(qfh[mf][s], klf[f], S[mf][f], 0, 0, 0);
                    S[mf][f] = __builtin_amdgcn_mfma_f32_16x16x32_bf16(qfl[mf][s], khf[f], S[mf][f], 0, 0, 0);
                }
        }

        __syncthreads();   // all waves done reading K; Kh region becomes P

        // ---- mask + online softmax + P write (fp16) ----
        _Float16* Pw = reinterpret_cast<_Float16*>(&Abuf[w * 2048]);
#pragma unroll
        for (int mf = 0; mf < 2; ++mf) {
#pragma unroll
            for (int f = 0; f < 4; ++f) {
                int key = ks + f * 16 + lr;
#pragma unroll
                for (int jj = 0; jj < 4; ++jj) {
                    int q = wq0 + mf * 16 + kg * 4 + jj;
                    if (key > q) S[mf][f][jj] = -3.0e38f;
                }
            }
#pragma unroll
            for (int jj = 0; jj < 4; ++jj) {
                float tm = fmaxf(fmaxf(S[mf][0][jj], S[mf][1][jj]),
                                 fmaxf(S[mf][2][jj], S[mf][3][jj]));
                tm = fmaxf(tm, __shfl_xor(tm, 1));
                tm = fmaxf(tm, __shfl_xor(tm, 2));
                tm = fmaxf(tm, __shfl_xor(tm, 4));
                tm = fmaxf(tm, __shfl_xor(tm, 8));
                float mnew = fmaxf(mrow[mf][jj], tm);
                float corr = __expf(mrow[mf][jj] - mnew);
                mrow[mf][jj] = mnew;
                float sum = 0.f;
#pragma unroll
                for (int f = 0; f < 4; ++f) {
                    float p = __expf(S[mf][f][jj] - mnew);
                    S[mf][f][jj] = p;
                    sum += p;
                }
                sum += __shfl_xor(sum, 1);
                sum += __shfl_xor(sum, 2);
                sum += __shfl_xor(sum, 4);
                sum += __shfl_xor(sum, 8);
                lrow[mf][jj] = lrow[mf][jj] * corr + sum;
#pragma unroll
                for (int df = 0; df < 8; ++df) O[mf][df][jj] *= corr;
            }
#pragma unroll
            for (int f = 0; f < 4; ++f)
#pragma unroll
                for (int jj = 0; jj < 4; ++jj) {
                    int qq  = mf * 16 + kg * 4 + jj;
                    int key = f * 16 + lr;
                    int e = qq * 64 + ((((key >> 3) ^ (qq & 7)) << 3) | (key & 7));
                    Pw[e] = (_Float16)S[mf][f][jj];
                }
        }

        // ---- PV: O += P (fp16) x V (fp16 hi/lo) ----
#pragma unroll
        for (int s = 0; s < 2; ++s) {
            f16x8 pa[2];
#pragma unroll
            for (int mf = 0; mf < 2; ++mf) {
                int qq = mf * 16 + lr;
                int e = w * 2048 + qq * 64 + (((4 * s + kg) ^ (qq & 7)) << 3);
                pa[mf] = __builtin_bit_cast(f16x8, *reinterpret_cast<const s16x8*>(&Abuf[e]));
            }
#pragma unroll
            for (int df = 0; df < 8; ++df) {
                int d = df * 16 + lr;
                int e = d * 64 + (((4 * s + kg) ^ (d & 7)) << 3);
                f16x8 vhf = __builtin_bit_cast(f16x8, *reinterpret_cast<const s16x8*>(&Bbuf[e]));
                f16x8 vlf = __builtin_bit_cast(f16x8, *reinterpret_cast<const s16x8*>(&Bbuf[8192 + e]));
#pragma unroll
                for (int mf = 0; mf < 2; ++mf) {
                    O[mf][df] = __builtin_amdgcn_mfma_f32_16x16x32_f16(pa[mf], vhf, O[mf][df], 0, 0, 0);
                    O[mf][df] = __builtin_amdgcn_mfma_f32_16x16x32_f16(pa[mf], vlf, O[mf][df], 0, 0, 0);
                }
            }
        }
        __syncthreads();   // P and V consumed; safe to restage
    }

    // ---- epilogue: O/l -> bf16 hi/lo at [B,T,H*128+d] ----
#pragma unroll
    for (int mf = 0; mf < 2; ++mf)
#pragma unroll
        for (int jj = 0; jj < 4; ++jj) {
            float rl = 1.0f / lrow[mf][jj];
            int q = wq0 + mf * 16 + kg * 4 + jj;
            size_t obase = ((size_t)(b * Tlen + q)) * Cdim + h * HD;
#pragma unroll
            for (int df = 0; df < 8; ++df) {
                float v = O[mf][df][jj] * rl;
                unsigned short hv = f2bf(v);
                Yhi[obase + df * 16 + lr] = hv;
                Ylo[obase + df * 16 + lr] = f2bf(v - bf2f(hv));
            }
        }
}

// ---------------------------------------------------------------------------
extern "C" void kernel_launch(void* const* d_in, const int* in_sizes, int n_in,
                              void* d_out, int out_size, void* d_ws, size_t ws_size,
                              hipStream_t stream)
{
    const float* x     = (const float*)d_in[0];
    const float* Wq    = (const float*)d_in[1];
    const float* Wkv   = (const float*)d_in[2];
    const float* Wproj = (const float*)d_in[3];
    float* out = (float*)d_out;

    const int M = Bsz * Tlen;                          // 4096

    // regions (bytes): A q_ws 32MB | B kv_ws 16MB | C x/Q 32MB | D wq/KV 16MB |
    //                  E wkv 8MB   | F wproj 16MB      (total 120MB)
    char* p = (char*)d_ws;
    float* q_ws  = (float*)p;                 p += (size_t)M * Cdim * 4;       // A
    float* kv_ws = (float*)p;                 p += (size_t)M * KVW  * 4;       // B
    unsigned short* xhi = (unsigned short*)p; p += (size_t)M * Cdim * 2;       // C1
    unsigned short* xlo = (unsigned short*)p; p += (size_t)M * Cdim * 2;       // C2
    unsigned short* wqh = (unsigned short*)p; p += (size_t)Cdim * Cdim * 2;    // D1
    unsigned short* wql = (unsigned short*)p; p += (size_t)Cdim * Cdim * 2;    // D2
    unsigned short* wkh = (unsigned short*)p; p += (size_t)KVW  * Cdim * 2;    // E1
    unsigned short* wkl = (unsigned short*)p; p += (size_t)KVW  * Cdim * 2;    // E2
    unsigned short* wph = (unsigned short*)p; p += (size_t)Cdim * Cdim * 2;    // F1
    unsigned short* wpl = (unsigned short*)p;                                   // F2

    // aliases (lifetimes verified):
    unsigned short* Qbh = xhi;                               // C: Q bf16 hi/lo after x dead
    unsigned short* Qbl = xlo;
    unsigned short* Kbh = wqh;                               // D: 4 x 4.2MB
    unsigned short* Kbl = wqh + (size_t)Bsz * NKV * Tlen * HD;
    unsigned short* Vbh = Kbl + (size_t)Bsz * NKV * Tlen * HD;
    unsigned short* Vbl = Vbh + (size_t)Bsz * NKV * Tlen * HD;
    unsigned short* Yhi = (unsigned short*)q_ws;             // A: after q_prep consumed q_ws
    unsigned short* Ylo = Yhi + (size_t)M * Cdim;

    dim3 blk(256);
    dim3 tblk(32, 8);

    // 1. convert inputs
    split_bf<<<dim3((M * Cdim / 4 + 255) / 256), blk, 0, stream>>>(x, xhi, xlo, M * Cdim / 4);
    conv_T<<<dim3(Cdim / 32, Cdim / 32), tblk, 0, stream>>>(Wq,    wqh, wql, Cdim, Cdim);
    conv_T<<<dim3(KVW  / 32, Cdim / 32), tblk, 0, stream>>>(Wkv,   wkh, wkl, Cdim, KVW);
    conv_T<<<dim3(Cdim / 32, Cdim / 32), tblk, 0, stream>>>(Wproj, wph, wpl, Cdim, Cdim);

    // 2. projections
    gemm_bf3<<<dim3(Cdim / 128, M / 128), blk, 0, stream>>>(xhi, xlo, wqh, wql, q_ws,  M, Cdim, Cdim);
    gemm_bf3<<<dim3(KVW  / 128, M / 128), blk, 0, stream>>>(xhi, xlo, wkh, wkl, kv_ws, M, KVW,  Cdim);

    // 3. preps: RoPE + split + relayout/swizzle
    q_prep<<<dim3(Bsz * NH  * Tlen * 64 / 256), blk, 0, stream>>>(q_ws, Qbh, Qbl);
    k_prep<<<dim3(Bsz * NKV * Tlen * 64 / 256), blk, 0, stream>>>(kv_ws, Kbh, Kbl);
    v_prep<<<dim3(Tlen / 32, Bsz * NKV * 4), tblk, 0, stream>>>(kv_ws, Vbh, Vbl);

    // 4. MFMA attention -> Y (bf16 hi/lo) in region A
    attn_mfma<<<dim3(512), blk, 0, stream>>>(Qbh, Qbl, Kbh, Kbl, Vbh, Vbl, Yhi, Ylo);

    // 5. output projection
    gemm_bf3<<<dim3(Cdim / 128, M / 128), blk, 0, stream>>>(Yhi, Ylo, wph, wpl, out, M, Cdim, Cdim);
}

// Round 5
// 570.721 us; speedup vs baseline: 3.3751x; 1.3661x over previous
//
#include <hip/hip_runtime.h>
#include <math.h>

#define Bsz   2
#define Tlen  2048
#define Cdim  2048
#define NH    16
#define NKV   4
#define HD    128
#define KVW   1024

typedef short    s16x8 __attribute__((ext_vector_type(8)));
typedef _Float16 f16x8 __attribute__((ext_vector_type(8)));
typedef _Float16 f16x2 __attribute__((ext_vector_type(2)));
typedef float    f32x4 __attribute__((ext_vector_type(4)));

static __device__ __forceinline__ unsigned short f2bf(float f) {
    unsigned int u = __float_as_uint(f);
    u = u + 0x7FFFu + ((u >> 16) & 1u);
    return (unsigned short)(u >> 16);
}
static __device__ __forceinline__ float bf2f(unsigned short h) {
    return __uint_as_float(((unsigned int)h) << 16);
}

#define GLL16(g, l) __builtin_amdgcn_global_load_lds( \
    (const __attribute__((address_space(1))) unsigned int*)(const void*)(g), \
    (__attribute__((address_space(3))) unsigned int*)(void*)(l), 16, 0, 0)

// ---------------------------------------------------------------------------
// split fp32 -> bf16 hi/lo (linear), 4 elems/thread
// ---------------------------------------------------------------------------
__global__ __launch_bounds__(256)
void split_bf(const float* __restrict__ in, unsigned short* __restrict__ hi,
              unsigned short* __restrict__ lo, int n4)
{
    int i = blockIdx.x * 256 + threadIdx.x;
    if (i >= n4) return;
    float4 v = reinterpret_cast<const float4*>(in)[i];
    ushort4 h, l;
    h.x = f2bf(v.x); l.x = f2bf(v.x - bf2f(h.x));
    h.y = f2bf(v.y); l.y = f2bf(v.y - bf2f(h.y));
    h.z = f2bf(v.z); l.z = f2bf(v.z - bf2f(h.z));
    h.w = f2bf(v.w); l.w = f2bf(v.w - bf2f(h.w));
    reinterpret_cast<ushort4*>(hi)[i] = h;
    reinterpret_cast<ushort4*>(lo)[i] = l;
}

// ---------------------------------------------------------------------------
// W[K][N] fp32 -> WT_hi/lo [N][K] bf16 (32x32 LDS tile transpose)
// ---------------------------------------------------------------------------
__global__ __launch_bounds__(256)
void conv_T(const float* __restrict__ W, unsigned short* __restrict__ Thi,
            unsigned short* __restrict__ Tlo, int K, int N)
{
    __shared__ float t[32][33];
    const int tx = threadIdx.x;
    const int ty = threadIdx.y;
    const int n0 = blockIdx.x * 32, k0 = blockIdx.y * 32;
#pragma unroll
    for (int j = 0; j < 4; ++j)
        t[ty + j * 8][tx] = W[(size_t)(k0 + ty + j * 8) * N + n0 + tx];
    __syncthreads();
#pragma unroll
    for (int j = 0; j < 4; ++j) {
        float v = t[tx][ty + j * 8];
        unsigned short h = f2bf(v);
        unsigned short l = f2bf(v - bf2f(h));
        size_t o = (size_t)(n0 + ty + j * 8) * K + k0 + tx;
        Thi[o] = h; Tlo[o] = l;
    }
}

// ---------------------------------------------------------------------------
// Split-bf16 3-pass MFMA GEMM (unchanged, proven)
// ---------------------------------------------------------------------------
__global__ __launch_bounds__(256)
void gemm_bf3(const unsigned short* __restrict__ Ah, const unsigned short* __restrict__ Al,
              const unsigned short* __restrict__ Bh, const unsigned short* __restrict__ Bl,
              float* __restrict__ Out, int M, int N, int K)
{
    __shared__ unsigned short Ahs[128][40], Als[128][40], Bhs[128][40], Bls[128][40];

    const int tid  = threadIdx.x;
    const int lane = tid & 63;
    const int w    = tid >> 6;
    const int wm   = w >> 1, wn = w & 1;
    const int m0   = blockIdx.y * 128, n0 = blockIdx.x * 128;
    const int lr   = lane & 15;
    const int kg   = lane >> 4;

    const int srow = tid >> 2;
    const int skg  = tid & 3;

    f32x4 acc[4][4];
#pragma unroll
    for (int i = 0; i < 4; ++i)
#pragma unroll
        for (int j = 0; j < 4; ++j) acc[i][j] = (f32x4){0.f, 0.f, 0.f, 0.f};

    for (int kt = 0; kt < K; kt += 32) {
#pragma unroll
        for (int t = 0; t < 2; ++t) {
            const int row = srow + t * 64;
            const size_t ga = (size_t)(m0 + row) * K + kt + skg * 8;
            const size_t gb = (size_t)(n0 + row) * K + kt + skg * 8;
            *reinterpret_cast<s16x8*>(&Ahs[row][skg * 8]) =
                *reinterpret_cast<const s16x8*>(&Ah[ga]);
            *reinterpret_cast<s16x8*>(&Als[row][skg * 8]) =
                *reinterpret_cast<const s16x8*>(&Al[ga]);
            *reinterpret_cast<s16x8*>(&Bhs[row][skg * 8]) =
                *reinterpret_cast<const s16x8*>(&Bh[gb]);
            *reinterpret_cast<s16x8*>(&Bls[row][skg * 8]) =
                *reinterpret_cast<const s16x8*>(&Bl[gb]);
        }
        __syncthreads();

        s16x8 ah[4], al[4], bh[4], bl[4];
#pragma unroll
        for (int f = 0; f < 4; ++f) {
            ah[f] = *reinterpret_cast<const s16x8*>(&Ahs[wm * 64 + f * 16 + lr][kg * 8]);
            al[f] = *reinterpret_cast<const s16x8*>(&Als[wm * 64 + f * 16 + lr][kg * 8]);
            bh[f] = *reinterpret_cast<const s16x8*>(&Bhs[wn * 64 + f * 16 + lr][kg * 8]);
            bl[f] = *reinterpret_cast<const s16x8*>(&Bls[wn * 64 + f * 16 + lr][kg * 8]);
        }
#pragma unroll
        for (int mf = 0; mf < 4; ++mf)
#pragma unroll
            for (int nf = 0; nf < 4; ++nf)
                acc[mf][nf] = __builtin_amdgcn_mfma_f32_16x16x32_bf16(
                    ah[mf], bh[nf], acc[mf][nf], 0, 0, 0);
#pragma unroll
        for (int mf = 0; mf < 4; ++mf)
#pragma unroll
            for (int nf = 0; nf < 4; ++nf)
                acc[mf][nf] = __builtin_amdgcn_mfma_f32_16x16x32_bf16(
                    ah[mf], bl[nf], acc[mf][nf], 0, 0, 0);
#pragma unroll
        for (int mf = 0; mf < 4; ++mf)
#pragma unroll
            for (int nf = 0; nf < 4; ++nf)
                acc[mf][nf] = __builtin_amdgcn_mfma_f32_16x16x32_bf16(
                    al[mf], bh[nf], acc[mf][nf], 0, 0, 0);
        __syncthreads();
    }

#pragma unroll
    for (int mf = 0; mf < 4; ++mf)
#pragma unroll
        for (int nf = 0; nf < 4; ++nf)
#pragma unroll
            for (int j = 0; j < 4; ++j)
                Out[(size_t)(m0 + wm * 64 + mf * 16 + kg * 4 + j) * N
                    + (n0 + wn * 64 + nf * 16 + lr)] = acc[mf][nf][j];
}

// ---------------------------------------------------------------------------
// q_prep: q_ws [B,T,2048] f32 -> RoPE -> *scale -> Qh [B,H,T,128] bf16 (hi only)
// ---------------------------------------------------------------------------
__global__ __launch_bounds__(256)
void q_prep(const float* __restrict__ q_ws, unsigned short* __restrict__ Qh)
{
    int i = blockIdx.x * 256 + threadIdx.x;       // (b,h,t,j)
    int j = i & 63;
    int t = (i >> 6) & 2047;
    int h = (i >> 17) & 15;
    int b = i >> 21;
    const float scale = 0.08838834764831845f;     // 1/sqrt(128)
    size_t src = ((size_t)(b * Tlen + t)) * Cdim + h * HD;
    float x1 = q_ws[src + j], x2 = q_ws[src + j + 64];
    float theta = powf(10000.0f, -(float)(2 * j) * (1.0f / 128.0f));
    float s, c; sincosf((float)t * theta, &s, &c);
    float o1 = (x1 * c - x2 * s) * scale;
    float o2 = (x2 * c + x1 * s) * scale;
    size_t dst = ((size_t)((b * NH + h) * Tlen + t)) * HD;
    Qh[dst + j]      = f2bf(o1);
    Qh[dst + j + 64] = f2bf(o2);
}

// ---------------------------------------------------------------------------
// k_prep: kv_ws K-part -> RoPE -> Kh/Kl [B,KV,T,128] bf16, LINEAR layout
// ---------------------------------------------------------------------------
__global__ __launch_bounds__(256)
void k_prep(const float* __restrict__ kv_ws, unsigned short* __restrict__ Kh,
            unsigned short* __restrict__ Kl)
{
    int i = blockIdx.x * 256 + threadIdx.x;       // (b,kh,t,j)
    int j = i & 63;
    int t = (i >> 6) & 2047;
    int kh = (i >> 17) & 3;
    int b = i >> 19;
    size_t src = ((size_t)(b * Tlen + t)) * KVW + kh * HD;
    float x1 = kv_ws[src + j], x2 = kv_ws[src + j + 64];
    float theta = powf(10000.0f, -(float)(2 * j) * (1.0f / 128.0f));
    float s, c; sincosf((float)t * theta, &s, &c);
    float o1 = x1 * c - x2 * s;
    float o2 = x2 * c + x1 * s;
    size_t row = ((size_t)((b * NKV + kh) * Tlen + t)) * HD;
    unsigned short h1 = f2bf(o1), h2 = f2bf(o2);
    Kh[row + j]      = h1; Kl[row + j]      = f2bf(o1 - bf2f(h1));
    Kh[row + j + 64] = h2; Kl[row + j + 64] = f2bf(o2 - bf2f(h2));
}

// ---------------------------------------------------------------------------
// v_prep: kv_ws V-part -> Vt [B,KV,128,2048] fp16 transposed, LINEAR layout
// ---------------------------------------------------------------------------
__global__ __launch_bounds__(256)
void v_prep(const float* __restrict__ kv_ws, unsigned short* __restrict__ Vt)
{
    __shared__ float tile[32][33];
    int tx = threadIdx.x, ty = threadIdx.y;
    int t0 = blockIdx.x * 32;
    int z  = blockIdx.y;                 // (b*NKV+kh)*4 + dblk
    int dblk = z & 3;
    int bk   = z >> 2;                   // b*NKV + kh
    int d0 = dblk * 32;
    int b = bk >> 2, kh = bk & 3;
#pragma unroll
    for (int jj = 0; jj < 4; ++jj) {
        int t = t0 + ty + jj * 8;
        tile[ty + jj * 8][tx] =
            kv_ws[((size_t)(b * Tlen + t)) * KVW + 512 + kh * HD + d0 + tx];
    }
    __syncthreads();
#pragma unroll
    for (int jj = 0; jj < 4; ++jj) {
        int d = d0 + ty + jj * 8;
        int t = t0 + tx;
        float v = tile[tx][ty + jj * 8];
        _Float16 vh = (_Float16)v;
        Vt[((size_t)bk * HD + d) * Tlen + t] = __builtin_bit_cast(unsigned short, vh);
    }
}

// ---------------------------------------------------------------------------
// MFMA flash attention v2: swapped-operand QK (S^T in regs), no P LDS,
// KBLK=32, double-buffered LDS (2 x 24KB) with counted vmcnt(6), raw barriers.
// Block = (b,h,128 q rows), 4 waves x 32 q. QK 2-pass (Kh+Kl)*Qh; PV fp16.
// ---------------------------------------------------------------------------
__global__ __launch_bounds__(256, 2)
void attn_mfma(const unsigned short* __restrict__ Qh,
               const unsigned short* __restrict__ Kh, const unsigned short* __restrict__ Kl,
               const unsigned short* __restrict__ Vt,
               unsigned short* __restrict__ Yhi, unsigned short* __restrict__ Ylo)
{
    // per buffer (halfword offsets): Khi [0,4096) | Klo [4096,8192) | V [8192,12288)
    __shared__ __align__(16) unsigned short lds[24576];   // 48KB

    const int tid  = threadIdx.x;
    const int lane = tid & 63;
    const int w    = tid >> 6;
    const int lr   = lane & 15;
    const int kg   = lane >> 4;

    // balanced dispatch: first 256 blocks qb=15..8 (desc), next 256 qb=0..7 (asc)
    const int z  = blockIdx.x;
    const int qb = (z < 256) ? (15 - (z >> 5)) : ((z - 256) >> 5);
    const int bh = z & 31;
    const int b  = bh >> 4, h = bh & 15;
    const int kh = h >> 2;
    const int q0 = qb * 128;
    const int wq0 = q0 + w * 32;

    const size_t kbase = (size_t)((b * NKV + kh) * Tlen) * HD;
    const size_t vbase = (size_t)(b * NKV + kh) * HD * Tlen;

    // ---- Q fragments (bf16 hi only), once per block ----
    const size_t qrowbase = (size_t)((b * NH + h) * Tlen);
    s16x8 qf[2][4];
#pragma unroll
    for (int mf = 0; mf < 2; ++mf)
#pragma unroll
        for (int s = 0; s < 4; ++s) {
            size_t e = (qrowbase + wq0 + mf * 16 + lr) * HD + (4 * s + kg) * 8;
            qf[mf][s] = *reinterpret_cast<const s16x8*>(&Qh[e]);
        }
    asm volatile("s_waitcnt vmcnt(0)" ::: "memory");   // only GLLs in flight inside loop

    f32x4 O[2][8];
#pragma unroll
    for (int mf = 0; mf < 2; ++mf)
#pragma unroll
        for (int df = 0; df < 8; ++df) O[mf][df] = (f32x4){0.f, 0.f, 0.f, 0.f};
    float mrow[2] = {-3.0e38f, -3.0e38f};
    float lrow[2] = {0.f, 0.f};

    const int nt = 4 * (qb + 1);

    auto stage = [&](int bufsel, int ks) {
        const int B = bufsel * 12288;
#pragma unroll
        for (int i = 0; i < 2; ++i) {              // K hi + lo: 512 chunks each
            int c   = i * 256 + tid;               // 0..511
            int key = c >> 4, cc = c & 15;
            int lc  = cc ^ (key & 7);
            size_t src = kbase + (size_t)(ks + key) * HD + lc * 8;
            GLL16(&Kh[src], &lds[B + (i * 256 + w * 64) * 8]);
            GLL16(&Kl[src], &lds[B + 4096 + (i * 256 + w * 64) * 8]);
        }
#pragma unroll
        for (int i = 0; i < 2; ++i) {              // V: 512 chunks
            int c  = i * 256 + tid;
            int d  = c >> 2, cc = c & 3;
            int lc = cc ^ ((d >> 1) & 3);
            size_t src = vbase + (size_t)d * Tlen + ks + lc * 8;
            GLL16(&Vt[src], &lds[B + 8192 + (i * 256 + w * 64) * 8]);
        }
    };

    stage(0, 0);

    for (int t = 0; t < nt; ++t) {
        if (t + 1 < nt) {
            stage((t + 1) & 1, (t + 1) * 32);
            asm volatile("s_waitcnt vmcnt(6)" ::: "memory");   // tile t's 6 done
        } else {
            asm volatile("s_waitcnt vmcnt(0)" ::: "memory");
        }
        __builtin_amdgcn_s_barrier();

        const int ks = t * 32;
        if (ks <= wq0 + 31) {                       // wave has >=1 visible key
            const int B = (t & 1) * 12288;

            // ---- QK^T swapped: S^T[key][q] = (Kh+Kl) x Qh, 2-pass ----
            f32x4 st[2][2];
#pragma unroll
            for (int mf = 0; mf < 2; ++mf)
#pragma unroll
                for (int f = 0; f < 2; ++f) st[mf][f] = (f32x4){0.f, 0.f, 0.f, 0.f};
#pragma unroll
            for (int s = 0; s < 4; ++s) {
                s16x8 khf[2], klf[2];
#pragma unroll
                for (int f = 0; f < 2; ++f) {
                    int key = f * 16 + lr;
                    int e = B + key * 128 + (((s * 4 + kg) ^ (key & 7)) << 3);
                    khf[f] = *reinterpret_cast<const s16x8*>(&lds[e]);
                    klf[f] = *reinterpret_cast<const s16x8*>(&lds[e + 4096]);
                }
#pragma unroll
                for (int mf = 0; mf < 2; ++mf)
#pragma unroll
                    for (int f = 0; f < 2; ++f) {
                        st[mf][f] = __builtin_amdgcn_mfma_f32_16x16x32_bf16(
                            khf[f], qf[mf][s], st[mf][f], 0, 0, 0);
                        st[mf][f] = __builtin_amdgcn_mfma_f32_16x16x32_bf16(
                            klf[f], qf[mf][s], st[mf][f], 0, 0, 0);
                    }
            }

            // ---- mask + online softmax (q = col = lr) + pack P to B-frag ----
            f16x8 pb[2];
#pragma unroll
            for (int mf = 0; mf < 2; ++mf) {
                const int q = wq0 + mf * 16 + lr;
#pragma unroll
                for (int f = 0; f < 2; ++f)
#pragma unroll
                    for (int jj = 0; jj < 4; ++jj) {
                        int key = ks + f * 16 + kg * 4 + jj;
                        if (key > q) st[mf][f][jj] = -3.0e38f;
                    }
                float tm = st[mf][0][0];
#pragma unroll
                for (int f = 0; f < 2; ++f)
#pragma unroll
                    for (int jj = 0; jj < 4; ++jj) tm = fmaxf(tm, st[mf][f][jj]);
                tm = fmaxf(tm, __shfl_xor(tm, 16));
                tm = fmaxf(tm, __shfl_xor(tm, 32));
                float mnew = fmaxf(mrow[mf], tm);
                float corr = __expf(mrow[mf] - mnew);
                mrow[mf] = mnew;
                float sum = 0.f;
#pragma unroll
                for (int f = 0; f < 2; ++f)
#pragma unroll
                    for (int jj = 0; jj < 4; ++jj) {
                        float p = __expf(st[mf][f][jj] - mnew);
                        st[mf][f][jj] = p;
                        sum += p;
                    }
                sum += __shfl_xor(sum, 16);
                sum += __shfl_xor(sum, 32);
                lrow[mf] = lrow[mf] * corr + sum;
#pragma unroll
                for (int df = 0; df < 8; ++df)
#pragma unroll
                    for (int jj = 0; jj < 4; ++jj) O[mf][df][jj] *= corr;

                // pack: lane (lr,kg) needs keys 8kg..8kg+7 at q=lr
                int A0 = __builtin_bit_cast(int, __builtin_amdgcn_cvt_pkrtz(st[mf][0][0], st[mf][0][1]));
                int A1 = __builtin_bit_cast(int, __builtin_amdgcn_cvt_pkrtz(st[mf][0][2], st[mf][0][3]));
                int B0 = __builtin_bit_cast(int, __builtin_amdgcn_cvt_pkrtz(st[mf][1][0], st[mf][1][1]));
                int B1 = __builtin_bit_cast(int, __builtin_amdgcn_cvt_pkrtz(st[mf][1][2], st[mf][1][3]));
                int s0 = (lane & 15) + 32 * (kg & 1);      // src lane kg'=2(kg&1)
                int s1 = s0 + 16;                           // src lane kg'+1
                int a0 = __shfl(A0, s0), b0 = __shfl(B0, s0);
                int a1 = __shfl(A1, s0), b1 = __shfl(B1, s0);
                int a2 = __shfl(A0, s1), b2 = __shfl(B0, s1);
                int a3 = __shfl(A1, s1), b3 = __shfl(B1, s1);
                bool hiF = (kg >= 2);
                int4 pw = { hiF ? b0 : a0, hiF ? b1 : a1,
                            hiF ? b2 : a2, hiF ? b3 : a3 };
                pb[mf] = __builtin_bit_cast(f16x8, pw);
            }

            // ---- PV: O^T[d][q] += V^T x P ----
#pragma unroll
            for (int df = 0; df < 8; ++df) {
                int d = df * 16 + lr;
                int e = B + 8192 + d * 32 + ((kg ^ ((d >> 1) & 3)) << 3);
                f16x8 vf = __builtin_bit_cast(f16x8,
                    *reinterpret_cast<const s16x8*>(&lds[e]));
                O[0][df] = __builtin_amdgcn_mfma_f32_16x16x32_f16(vf, pb[0], O[0][df], 0, 0, 0);
                O[1][df] = __builtin_amdgcn_mfma_f32_16x16x32_f16(vf, pb[1], O[1][df], 0, 0, 0);
            }
        }
        __builtin_amdgcn_s_barrier();
    }

    // ---- epilogue: O^T/l -> bf16 hi/lo at Y[b,t=q][h*128+d], 8B stores ----
#pragma unroll
    for (int mf = 0; mf < 2; ++mf) {
        const int q = wq0 + mf * 16 + lr;
        const float rl = 1.0f / lrow[mf];
        const size_t obase = ((size_t)(b * Tlen + q)) * Cdim + h * HD;
#pragma unroll
        for (int df = 0; df < 8; ++df) {
            ushort4 hv, lv;
#pragma unroll
            for (int jj = 0; jj < 4; ++jj) {
                float v = O[mf][df][jj] * rl;
                unsigned short hb = f2bf(v);
                (&hv.x)[jj] = hb;
                (&lv.x)[jj] = f2bf(v - bf2f(hb));
            }
            size_t e = obase + df * 16 + kg * 4;
            *reinterpret_cast<ushort4*>(&Yhi[e]) = hv;
            *reinterpret_cast<ushort4*>(&Ylo[e]) = lv;
        }
    }
}

// ---------------------------------------------------------------------------
extern "C" void kernel_launch(void* const* d_in, const int* in_sizes, int n_in,
                              void* d_out, int out_size, void* d_ws, size_t ws_size,
                              hipStream_t stream)
{
    const float* x     = (const float*)d_in[0];
    const float* Wq    = (const float*)d_in[1];
    const float* Wkv   = (const float*)d_in[2];
    const float* Wproj = (const float*)d_in[3];
    float* out = (float*)d_out;

    const int M = Bsz * Tlen;                          // 4096

    char* p = (char*)d_ws;
    float* q_ws  = (float*)p;                 p += (size_t)M * Cdim * 4;       // A
    float* kv_ws = (float*)p;                 p += (size_t)M * KVW  * 4;       // B
    unsigned short* xhi = (unsigned short*)p; p += (size_t)M * Cdim * 2;       // C1
    unsigned short* xlo = (unsigned short*)p; p += (size_t)M * Cdim * 2;       // C2
    unsigned short* wqh = (unsigned short*)p; p += (size_t)Cdim * Cdim * 2;    // D1
    unsigned short* wql = (unsigned short*)p; p += (size_t)Cdim * Cdim * 2;    // D2
    unsigned short* wkh = (unsigned short*)p; p += (size_t)KVW  * Cdim * 2;    // E1
    unsigned short* wkl = (unsigned short*)p; p += (size_t)KVW  * Cdim * 2;    // E2
    unsigned short* wph = (unsigned short*)p; p += (size_t)Cdim * Cdim * 2;    // F1
    unsigned short* wpl = (unsigned short*)p;                                   // F2

    // aliases (lifetimes): Q into C (x dead after gemms); K/V into D (wq dead);
    // Y into A (q_ws dead after q_prep)
    const size_t KVE = (size_t)Bsz * NKV * Tlen * HD;        // 2.097M elems
    unsigned short* Qbh = xhi;
    unsigned short* Kbh = wqh;
    unsigned short* Kbl = wqh + KVE;
    unsigned short* Vbt = wqh + 2 * KVE;
    unsigned short* Yhi = (unsigned short*)q_ws;
    unsigned short* Ylo = Yhi + (size_t)M * Cdim;

    dim3 blk(256);
    dim3 tblk(32, 8);

    // 1. convert inputs
    split_bf<<<dim3((M * Cdim / 4 + 255) / 256), blk, 0, stream>>>(x, xhi, xlo, M * Cdim / 4);
    conv_T<<<dim3(Cdim / 32, Cdim / 32), tblk, 0, stream>>>(Wq,    wqh, wql, Cdim, Cdim);
    conv_T<<<dim3(KVW  / 32, Cdim / 32), tblk, 0, stream>>>(Wkv,   wkh, wkl, Cdim, KVW);
    conv_T<<<dim3(Cdim / 32, Cdim / 32), tblk, 0, stream>>>(Wproj, wph, wpl, Cdim, Cdim);

    // 2. projections
    gemm_bf3<<<dim3(Cdim / 128, M / 128), blk, 0, stream>>>(xhi, xlo, wqh, wql, q_ws,  M, Cdim, Cdim);
    gemm_bf3<<<dim3(KVW  / 128, M / 128), blk, 0, stream>>>(xhi, xlo, wkh, wkl, kv_ws, M, KVW,  Cdim);

    // 3. preps: RoPE + split + relayout (all-linear global layouts)
    q_prep<<<dim3(Bsz * NH  * Tlen * 64 / 256), blk, 0, stream>>>(q_ws, Qbh);
    k_prep<<<dim3(Bsz * NKV * Tlen * 64 / 256), blk, 0, stream>>>(kv_ws, Kbh, Kbl);
    v_prep<<<dim3(Tlen / 32, Bsz * NKV * 4), tblk, 0, stream>>>(kv_ws, Vbt);

    // 4. MFMA attention v2 -> Y (bf16 hi/lo) in region A
    attn_mfma<<<dim3(512), blk, 0, stream>>>(Qbh, Kbh, Kbl, Vbt, Yhi, Ylo);

    // 5. output projection
    gemm_bf3<<<dim3(Cdim / 128, M / 128), blk, 0, stream>>>(Yhi, Ylo, wph, wpl, out, M, Cdim, Cdim);
}